// Round 14
// baseline (104.525 us; speedup 1.0000x reference)
//
#include <hip/hip_runtime.h>

#define T_SEQ 4096
#define NBATCH 4
#define CDIM 1024
#define NHEAD 64
#define SCALE (1.0f / 32.0f)
#define LOG2E 1.4426950408889634f
#define BT (NBATCH * T_SEQ)
#define NW 8             // waves per attn block (key-split factor)
#define WREG 8960        // per-wave LDS region bytes: o[32][68] f32 + m + l
#define THR2 11.0f       // defer-max threshold in log2 domain (~8 nats)

typedef __bf16 bf16x8 __attribute__((ext_vector_type(8)));
typedef float f32x4 __attribute__((ext_vector_type(4)));
typedef float f32x16 __attribute__((ext_vector_type(16)));
typedef unsigned long long u64;

__device__ __forceinline__ unsigned short f2bf(float f) {
  union { float f; unsigned u; } x;
  x.f = f;
  unsigned r = x.u + 0x7FFFu + ((x.u >> 16) & 1u);
  return (unsigned short)(r >> 16);
}

// RNE pack of two f32 -> one u32 of 2 bf16 (correctness verified R10-R13)
__device__ __forceinline__ unsigned cvt_pk(float lo, float hi) {
  unsigned d;
  asm("v_cvt_pk_bf16_f32 %0, %1, %2" : "=v"(d) : "v"(lo), "v"(hi));
  return d;
}

__device__ __forceinline__ f32x4 mfma16(bf16x8 a, bf16x8 b, f32x4 c) {
  return __builtin_amdgcn_mfma_f32_16x16x32_bf16(a, b, c, 0, 0, 0);
}

__device__ __forceinline__ f32x16 mfma32(bf16x8 a, bf16x8 b, f32x16 c) {
  return __builtin_amdgcn_mfma_f32_32x32x16_bf16(a, b, c, 0, 0, 0);
}

// ---------------------------------------------------------------------------
// Kernel 1: Wt[c][k] = W*(k, c%64) * (c<64 ? SCALE*log2e : 1), bf16.
// ---------------------------------------------------------------------------
__global__ void prep_w(const float* __restrict__ Wq, const float* __restrict__ Wk,
                       const float* __restrict__ Wv, unsigned short* __restrict__ Wt) {
  int c = blockIdx.x;
  const float* W = (c < 64) ? Wq : (c < 128) ? Wk : Wv;
  int cc = c & 63;
  float sc = (c < 64) ? (SCALE * LOG2E) : 1.0f;
  for (int k = threadIdx.x; k < CDIM; k += blockDim.x)
    Wt[c * CDIM + k] = f2bf(W[k * NHEAD + cc] * sc);
}

// ---------------------------------------------------------------------------
// Kernel 2: fused QKV projection (unchanged from R13).
// M-tile = 32 rows, 512 blocks x 4 waves -> 2 blocks/CU; 12 Wt B-fragment
// loads per k0-step hoisted so they're simultaneously in flight.
// ---------------------------------------------------------------------------
__global__ __launch_bounds__(256) void proj_qkv(
    const float* __restrict__ x, const unsigned short* __restrict__ Wt,
    unsigned short* __restrict__ qws, unsigned short* __restrict__ kws,
    unsigned short* __restrict__ vtws) {
  __shared__ unsigned short xlds[32][136];  // 128 bf16 + 8 pad
  const int tid = threadIdx.x;
  const int lane = tid & 63;
  const int w = tid >> 6;
  const int g = lane >> 4;
  const int c15 = lane & 15;
  const int rb = blockIdx.x * 32;

  f32x4 acc[2][3];
  for (int i = 0; i < 2; i++)
    for (int j = 0; j < 3; j++) acc[i][j] = (f32x4){0.f, 0.f, 0.f, 0.f};

  const int sr = tid >> 3;         // staging row 0..31
  const int scc = (tid & 7) * 16;  // staging col base (floats)
  const float* xrow = x + (size_t)(rb + sr) * CDIM + scc;

  float4 cur[4];
  for (int i = 0; i < 4; i++) cur[i] = *(const float4*)(xrow + i * 4);

  for (int k0 = 0; k0 < CDIM; k0 += 128) {
    unsigned short pk[16];
    for (int i = 0; i < 4; i++) {
      pk[i * 4 + 0] = f2bf(cur[i].x);
      pk[i * 4 + 1] = f2bf(cur[i].y);
      pk[i * 4 + 2] = f2bf(cur[i].z);
      pk[i * 4 + 3] = f2bf(cur[i].w);
    }
    *(bf16x8*)&xlds[sr][scc] = *(bf16x8*)&pk[0];
    *(bf16x8*)&xlds[sr][scc + 8] = *(bf16x8*)&pk[8];
    __syncthreads();
    if (k0 + 128 < CDIM)
      for (int i = 0; i < 4; i++)
        cur[i] = *(const float4*)(xrow + k0 + 128 + i * 4);

    bf16x8 wfrag[4][3];
    for (int kk = 0; kk < 4; kk++)
      for (int bn = 0; bn < 3; bn++) {
        int col = w * 48 + bn * 16 + c15;
        wfrag[kk][bn] =
            *(const bf16x8*)&Wt[(size_t)col * CDIM + k0 + kk * 32 + g * 8];
      }

    for (int kk = 0; kk < 4; kk++) {
      bf16x8 a[2];
      for (int mt = 0; mt < 2; mt++)
        a[mt] = *(bf16x8*)&xlds[mt * 16 + c15][kk * 32 + g * 8];
      for (int bn = 0; bn < 3; bn++)
        for (int mt = 0; mt < 2; mt++)
          acc[mt][bn] = mfma16(a[mt], wfrag[kk][bn], acc[mt][bn]);
    }
    __syncthreads();
  }

  for (int mt = 0; mt < 2; mt++)
    for (int bn = 0; bn < 3; bn++) {
      int col = w * 48 + bn * 16 + c15;
      int row0 = rb + mt * 16 + 4 * g;
      for (int r = 0; r < 4; r++) {
        unsigned short v = f2bf(acc[mt][bn][r]);
        int t = row0 + r;
        if (col < 64)
          qws[(size_t)t * 64 + col] = v;
        else if (col < 128)
          kws[(size_t)t * 64 + (col - 64)] = v;
        else
          vtws[(size_t)(col - 128) * BT + t] = v;
      }
    }
}

// ---------------------------------------------------------------------------
// Kernel 3: causal flash attention, 32x32 MFMA + register-resident P.
// R13 lesson: 4 structural variants all ~42us; all pipes <35% busy =
// latency-bound. The invariant was GRID = 256 = 1 block/CU. This round's
// single variable: 512 blocks (1 q-tile each, pair-interleaved qt order so
// co-resident blocks balance) + launch_bounds(512,4): VGPR 96 fits the 128
// cap -> 2 blocks/CU = 4 waves/SIMD, doubling latency-hiding TLP.
// Structure (R13, verified): S = mfma32(K,Q), lane l holds 16 S of q-row
// l&31 (keys (r&3)+8*(r>>2)+4*hi); row max/sum in-lane + one xor32; P packed
// via cvt_pk and redistributed by 8 xor32 shuffles into PV B-frags; PV =
// mfma32(V, P~); l via VALU sum. No LDS in the loop, no fences.
// Per-wave WREG 8960 B (epilogue only): o[32][68] f32 @0, m @8704, l @8832.
// ---------------------------------------------------------------------------
__global__ __launch_bounds__(512, 4) void attn_fwd(
    const unsigned short* __restrict__ qws, const unsigned short* __restrict__ kws,
    const unsigned short* __restrict__ vtws, float* __restrict__ out) {
  __shared__ __align__(16) char smem[NW * WREG];  // 70 KiB -> 2 blocks/CU
  const int tid = threadIdx.x;
  const int lane = tid & 63;
  const int w = tid >> 6;
  const int q31 = lane & 31;   // q-row within tile
  const int hi = lane >> 5;    // key-set selector (A/B)
  const int b = blockIdx.x >> 7;
  const int j = blockIdx.x & 127;
  const int qt = (j & 1) ? (127 - (j >> 1)) : (j >> 1);  // pair-balanced
  const int qb = qt * 32;
  const int nsteps = qt + 1;  // 32-key steps
  const size_t rowbase = (size_t)b * T_SEQ;
  char* wbase = smem + w * WREG;

  // Q B-frag: col=q31, k = h2*16 + hi*8 + j
  bf16x8 qf[4];
  for (int h2 = 0; h2 < 4; h2++)
    qf[h2] = *(const bf16x8*)&qws[(rowbase + qb + q31) * 64 + h2 * 16 + hi * 8];

  f32x16 o[2];
  o[0] = (f32x16)0.f;
  o[1] = (f32x16)0.f;
  float mrow = -1e30f;
  float lrun = 0.f;

  for (int st = w; st < nsteps; st += NW) {
    const int kt = st * 32;
    // K A-frag: row = key q31, k = h2*16 + hi*8 + j
    bf16x8 ka[4];
    for (int h2 = 0; h2 < 4; h2++)
      ka[h2] = *(const bf16x8*)&kws[(rowbase + kt + q31) * 64 + h2 * 16 + hi * 8];
    // V A-frag: row = d (nt*32 + q31), k = keys ki*16 + hi*8 + j
    bf16x8 va[2][2];
    for (int nt = 0; nt < 2; nt++)
      for (int ki = 0; ki < 2; ki++)
        va[nt][ki] = *(const bf16x8*)&vtws[(size_t)(nt * 32 + q31) * BT +
                                           rowbase + kt + ki * 16 + hi * 8];

    // S = mfma32(K, Q): lane holds S[q=q31][key = kt + (r&3)+8*(r>>2)+4*hi]
    f32x16 s = (f32x16)0.f;
    for (int h2 = 0; h2 < 4; h2++) s = mfma32(ka[h2], qf[h2], s);

    float sv[16];
    for (int r = 0; r < 16; r++) sv[r] = s[r];

    if (st == nsteps - 1) {  // diagonal tile: causal mask
      for (int r = 0; r < 16; r++) {
        int key = kt + (r & 3) + 8 * (r >> 2) + 4 * hi;
        if (key > qb + q31) sv[r] = -1e30f;
      }
    }

    // row max: in-lane tree + one xor32
    float t01 = fmaxf(sv[0], sv[1]), t23 = fmaxf(sv[2], sv[3]);
    float t45 = fmaxf(sv[4], sv[5]), t67 = fmaxf(sv[6], sv[7]);
    float t89 = fmaxf(sv[8], sv[9]), tab = fmaxf(sv[10], sv[11]);
    float tcd = fmaxf(sv[12], sv[13]), tef = fmaxf(sv[14], sv[15]);
    float t = fmaxf(fmaxf(fmaxf(t01, t23), fmaxf(t45, t67)),
                    fmaxf(fmaxf(t89, tab), fmaxf(tcd, tef)));
    t = fmaxf(t, __shfl_xor(t, 32));
    if (__any(t > mrow + THR2)) {  // defer-max (log2 domain)
      float mn = fmaxf(mrow, t);
      float a = exp2f(mrow - mn);
      mrow = mn;
      o[0] *= a;
      o[1] *= a;
      lrun *= a;
    }
    float p[16];
    for (int r = 0; r < 16; r++) p[r] = exp2f(sv[r] - mrow);

    // l: in-lane sum + xor32
    float ssum = 0.f;
    for (int r = 0; r < 16; r++) ssum += p[r];
    lrun += ssum + __shfl_xor(ssum, 32);

    // pack + swap halves: X[j]=(p[2j],p[2j+1]); Y[j]=partner X[j]
    unsigned X[8], Y[8];
    for (int jj = 0; jj < 8; jj++) X[jj] = cvt_pk(p[2 * jj], p[2 * jj + 1]);
    for (int jj = 0; jj < 8; jj++) Y[jj] = __shfl_xor(X[jj], 32);

    // PV B-frags (keys ki*16..+15): lane provides keys ki*16+hi*8..+7
    union { unsigned u[4]; bf16x8 v; } bf0, bf1;
    bf0.u[0] = hi ? Y[2] : X[0];
    bf0.u[1] = hi ? Y[3] : X[1];
    bf0.u[2] = hi ? X[2] : Y[0];
    bf0.u[3] = hi ? X[3] : Y[1];
    bf1.u[0] = hi ? Y[6] : X[4];
    bf1.u[1] = hi ? Y[7] : X[5];
    bf1.u[2] = hi ? X[6] : Y[4];
    bf1.u[3] = hi ? X[7] : Y[5];

    for (int nt = 0; nt < 2; nt++) {
      o[nt] = mfma32(va[nt][0], bf0.v, o[nt]);
      o[nt] = mfma32(va[nt][1], bf1.v, o[nt]);
    }
  }

  // ---- per-wave partials; o stride 68 f32 ----
  float* ow = (float*)wbase;
  float* mw = (float*)(wbase + 8704);
  float* lw = (float*)(wbase + 8832);
  for (int nt = 0; nt < 2; nt++)
    for (int r = 0; r < 16; r++) {
      int d = nt * 32 + (r & 3) + 8 * (r >> 2) + 4 * hi;
      ow[q31 * 68 + d] = o[nt][r];
    }
  if (hi == 0) {
    mw[q31] = mrow;
    lw[q31] = lrun;
  }
  __syncthreads();

  // ---- LSE-merge across 8 waves (log2 domain): 512 thr x 4 = 32x64 ----
  for (int i = 0; i < 4; i++) {
    int e = tid + i * 512;
    int row = e >> 6;
    int d = e & 63;
    float M = -1e30f;
    for (int ww = 0; ww < NW; ww++)
      M = fmaxf(M, ((const float*)(smem + ww * WREG + 8704))[row]);
    float L = 0.f, O = 0.f;
    for (int ww = 0; ww < NW; ww++) {
      float mv = ((const float*)(smem + ww * WREG + 8704))[row];
      float f = exp2f(mv - M);
      L += f * ((const float*)(smem + ww * WREG + 8832))[row];
      O += f * ((const float*)(smem + ww * WREG))[row * 68 + d];
    }
    out[(rowbase + qb + row) * 64 + d] = O / L;
  }
}

// ---------------------------------------------------------------------------
extern "C" void kernel_launch(void* const* d_in, const int* in_sizes, int n_in,
                              void* d_out, int out_size, void* d_ws, size_t ws_size,
                              hipStream_t stream) {
  const float* x = (const float*)d_in[0];
  const float* Wq = (const float*)d_in[1];
  const float* Wk = (const float*)d_in[2];
  const float* Wv = (const float*)d_in[3];
  float* out = (float*)d_out;

  char* ws = (char*)d_ws;
  unsigned short* Wt = (unsigned short*)(ws);                          // 384 KB
  unsigned short* qws = (unsigned short*)(ws + 393216);                // 2 MB
  unsigned short* kws = (unsigned short*)(ws + 393216 + 2097152);      // 2 MB
  unsigned short* vtws = (unsigned short*)(ws + 393216 + 2 * 2097152); // 2 MB

  prep_w<<<dim3(192), dim3(256), 0, stream>>>(Wq, Wk, Wv, Wt);
  proj_qkv<<<dim3(512), dim3(256), 0, stream>>>(x, Wt, qws, kws, vtws);
  attn_fwd<<<dim3(512), dim3(512), 0, stream>>>(qws, kws, vtws, out);
}

// Round 16
// 79.789 us; speedup vs baseline: 1.3100x; 1.3100x over previous
//
#include <hip/hip_runtime.h>

#define T_SEQ 4096
#define NBATCH 4
#define CDIM 1024
#define NHEAD 64
#define SCALE (1.0f / 32.0f)
#define LOG2E 1.4426950408889634f
#define BT (NBATCH * T_SEQ)
#define NW 8             // waves per attn block (key-split factor)
#define WREG 8960        // per-wave LDS region bytes: o[32][68] f32 + m + l

typedef __bf16 bf16x8 __attribute__((ext_vector_type(8)));
typedef float f32x4 __attribute__((ext_vector_type(4)));
typedef float f32x16 __attribute__((ext_vector_type(16)));

__device__ __forceinline__ unsigned short f2bf(float f) {
  union { float f; unsigned u; } x;
  x.f = f;
  unsigned r = x.u + 0x7FFFu + ((x.u >> 16) & 1u);
  return (unsigned short)(r >> 16);
}

// RNE pack of two f32 -> one u32 of 2 bf16 (correctness verified R10-R14)
__device__ __forceinline__ unsigned cvt_pk(float lo, float hi) {
  unsigned d;
  asm("v_cvt_pk_bf16_f32 %0, %1, %2" : "=v"(d) : "v"(lo), "v"(hi));
  return d;
}

// lane-half swap, VALU pipe: vdst.hi <-> vsrc.lo. ONLY safe with operands
// that are DISTINCT VALUES (distinct defs): R15 used it on a trivial copy
// (tc=t) and the allocator coalesced both "+v" operands into one VGPR ->
// in-place half-rotate instead of cross-swap -> absmax 1.2. X[0..7] are
// distinct defs, immune. Pairing swap(X0,X2) matches m214's verified
// recipe (swaps cvtpk(p[2i],..) with cvtpk(p[2i+4],..)).
__device__ __forceinline__ void swap32(unsigned& a, unsigned& b) {
  asm("v_permlane32_swap_b32 %0, %1" : "+v"(a), "+v"(b));
}

__device__ __forceinline__ f32x4 mfma16(bf16x8 a, bf16x8 b, f32x4 c) {
  return __builtin_amdgcn_mfma_f32_16x16x32_bf16(a, b, c, 0, 0, 0);
}

__device__ __forceinline__ f32x16 mfma32(bf16x8 a, bf16x8 b, f32x16 c) {
  return __builtin_amdgcn_mfma_f32_32x32x16_bf16(a, b, c, 0, 0, 0);
}

// ---------------------------------------------------------------------------
// Kernel 1: Wt[c][k] = W*(k, c%64) * (c<64 ? SCALE*log2e : 1), bf16.
// ---------------------------------------------------------------------------
__global__ void prep_w(const float* __restrict__ Wq, const float* __restrict__ Wk,
                       const float* __restrict__ Wv, unsigned short* __restrict__ Wt) {
  int c = blockIdx.x;
  const float* W = (c < 64) ? Wq : (c < 128) ? Wk : Wv;
  int cc = c & 63;
  float sc = (c < 64) ? (SCALE * LOG2E) : 1.0f;
  for (int k = threadIdx.x; k < CDIM; k += blockDim.x)
    Wt[c * CDIM + k] = f2bf(W[k * NHEAD + cc] * sc);
}

// ---------------------------------------------------------------------------
// Kernel 2: fused QKV projection, LDS DOUBLE-BUFFER (this round's change):
// compute from xlds[pb] while packing the prefetched x-chunk into xlds[pb^1]
// -> ONE barrier per k0-iter (was two), pack overlaps compute.
// M-tile = 32 rows, 512 blocks x 4 waves -> 2 blocks/CU; 12 Wt B-fragment
// loads hoisted & in flight before the MFMA chain.
// ---------------------------------------------------------------------------
__global__ __launch_bounds__(256) void proj_qkv(
    const float* __restrict__ x, const unsigned short* __restrict__ Wt,
    unsigned short* __restrict__ qws, unsigned short* __restrict__ kws,
    unsigned short* __restrict__ vtws) {
  __shared__ unsigned short xlds[2][32][136];  // 2 x (128 bf16 + 8 pad)
  const int tid = threadIdx.x;
  const int lane = tid & 63;
  const int w = tid >> 6;
  const int g = lane >> 4;
  const int c15 = lane & 15;
  const int rb = blockIdx.x * 32;

  f32x4 acc[2][3];
  for (int i = 0; i < 2; i++)
    for (int j = 0; j < 3; j++) acc[i][j] = (f32x4){0.f, 0.f, 0.f, 0.f};

  const int sr = tid >> 3;         // staging row 0..31
  const int scc = (tid & 7) * 16;  // staging col base (floats / bf16 cols)
  const float* xrow = x + (size_t)(rb + sr) * CDIM + scc;

  // prologue: load + pack chunk 0 into buffer 0
  {
    float4 cur[4];
    for (int i = 0; i < 4; i++) cur[i] = *(const float4*)(xrow + i * 4);
    unsigned short pk[16];
    for (int i = 0; i < 4; i++) {
      pk[i * 4 + 0] = f2bf(cur[i].x);
      pk[i * 4 + 1] = f2bf(cur[i].y);
      pk[i * 4 + 2] = f2bf(cur[i].z);
      pk[i * 4 + 3] = f2bf(cur[i].w);
    }
    *(bf16x8*)&xlds[0][sr][scc] = *(bf16x8*)&pk[0];
    *(bf16x8*)&xlds[0][sr][scc + 8] = *(bf16x8*)&pk[8];
  }
  __syncthreads();

  int pb = 0;
  for (int k0 = 0; k0 < CDIM; k0 += 128) {
    const bool more = (k0 + 128 < CDIM);
    // issue next x chunk first (full iteration of latency budget)
    float4 nxt[4];
    if (more)
      for (int i = 0; i < 4; i++)
        nxt[i] = *(const float4*)(xrow + k0 + 128 + i * 4);

    // 12 independent Wt loads in flight
    bf16x8 wfrag[4][3];
    for (int kk = 0; kk < 4; kk++)
      for (int bn = 0; bn < 3; bn++) {
        int col = w * 48 + bn * 16 + c15;
        wfrag[kk][bn] =
            *(const bf16x8*)&Wt[(size_t)col * CDIM + k0 + kk * 32 + g * 8];
      }

    // compute from buffer pb
    for (int kk = 0; kk < 4; kk++) {
      bf16x8 a[2];
      for (int mt = 0; mt < 2; mt++)
        a[mt] = *(bf16x8*)&xlds[pb][mt * 16 + c15][kk * 32 + g * 8];
      for (int bn = 0; bn < 3; bn++)
        for (int mt = 0; mt < 2; mt++)
          acc[mt][bn] = mfma16(a[mt], wfrag[kk][bn], acc[mt][bn]);
    }

    // pack next chunk into the other buffer (overlaps with other waves'
    // compute; barrier then publishes it and retires reads of pb)
    if (more) {
      unsigned short pk[16];
      for (int i = 0; i < 4; i++) {
        pk[i * 4 + 0] = f2bf(nxt[i].x);
        pk[i * 4 + 1] = f2bf(nxt[i].y);
        pk[i * 4 + 2] = f2bf(nxt[i].z);
        pk[i * 4 + 3] = f2bf(nxt[i].w);
      }
      *(bf16x8*)&xlds[pb ^ 1][sr][scc] = *(bf16x8*)&pk[0];
      *(bf16x8*)&xlds[pb ^ 1][sr][scc + 8] = *(bf16x8*)&pk[8];
    }
    __syncthreads();
    pb ^= 1;
  }

  for (int mt = 0; mt < 2; mt++)
    for (int bn = 0; bn < 3; bn++) {
      int col = w * 48 + bn * 16 + c15;
      int row0 = rb + mt * 16 + 4 * g;
      for (int r = 0; r < 4; r++) {
        unsigned short v = f2bf(acc[mt][bn][r]);
        int t = row0 + r;
        if (col < 64)
          qws[(size_t)t * 64 + col] = v;
        else if (col < 128)
          kws[(size_t)t * 64 + (col - 64)] = v;
        else
          vtws[(size_t)(col - 128) * BT + t] = v;
      }
    }
}

// ---------------------------------------------------------------------------
// Kernel 3: causal flash attention, 32x32 MFMA. Hybrid cross-lane (R15 fix):
//  - scalar row-max / row-sum: __shfl_xor(.,32) — R13-proven (R15's
//    permlane-on-a-copy hit the operand-coalescing trap; see swap32 note).
//  - P redistribution: 4 permlane32_swap on DISTINCT X values (replaces
//    8 shuffles + 8 cndmasks; matches m214's verified pairing).
//  - branchless rescale: a=exp2(mrow-mn) unconditionally (a=1 no-growth,
//    step0 a=0) — removes the divergent branch blocking pipelining.
// Shape (proven): 256 blocks x 8 waves, (512,2), in-block light/heavy
// halves; NO LDS / fences in loop. Per-wave WREG 8960 B epilogue only.
// ---------------------------------------------------------------------------
__global__ __launch_bounds__(512, 2) void attn_fwd(
    const unsigned short* __restrict__ qws, const unsigned short* __restrict__ kws,
    const unsigned short* __restrict__ vtws, float* __restrict__ out) {
  __shared__ __align__(16) char smem[NW * WREG];  // 70 KiB
  const int tid = threadIdx.x;
  const int lane = tid & 63;
  const int w = tid >> 6;
  const int q31 = lane & 31;   // q-row within tile
  const int hi = lane >> 5;    // key-set selector (A/B)
  const int b = blockIdx.x >> 6;
  const int pi = blockIdx.x & 63;
  const size_t rowbase = (size_t)b * T_SEQ;
  char* wbase = smem + w * WREG;

  for (int half = 0; half < 2; ++half) {
    const int qt = half ? (127 - pi) : pi;
    const int qb = qt * 32;
    const int nsteps = qt + 1;  // 32-key steps

    // Q B-frag: col=q31, k = h2*16 + hi*8 + j
    bf16x8 qf[4];
    for (int h2 = 0; h2 < 4; h2++)
      qf[h2] = *(const bf16x8*)&qws[(rowbase + qb + q31) * 64 + h2 * 16 + hi * 8];

    f32x16 o[2];
    o[0] = (f32x16)0.f;
    o[1] = (f32x16)0.f;
    float mrow = -1e30f;
    float lrun = 0.f;

    for (int st = w; st < nsteps; st += NW) {
      const int kt = st * 32;
      bf16x8 ka[4];
      for (int h2 = 0; h2 < 4; h2++)
        ka[h2] =
            *(const bf16x8*)&kws[(rowbase + kt + q31) * 64 + h2 * 16 + hi * 8];
      bf16x8 va[2][2];
      for (int nt = 0; nt < 2; nt++)
        for (int ki = 0; ki < 2; ki++)
          va[nt][ki] = *(const bf16x8*)&vtws[(size_t)(nt * 32 + q31) * BT +
                                             rowbase + kt + ki * 16 + hi * 8];

      // S = mfma32(K, Q): lane holds S[q=q31][key = kt + (r&3)+8*(r>>2)+4*hi]
      f32x16 s = (f32x16)0.f;
      for (int h2 = 0; h2 < 4; h2++) s = mfma32(ka[h2], qf[h2], s);

      float sv[16];
      for (int r = 0; r < 16; r++) sv[r] = s[r];

      if (st == nsteps - 1) {  // diagonal tile: causal mask (uniform branch)
        for (int r = 0; r < 16; r++) {
          int key = kt + (r & 3) + 8 * (r >> 2) + 4 * hi;
          if (key > qb + q31) sv[r] = -1e30f;
        }
      }

      // row max: in-lane tree + one shfl_xor(32) [R13-proven]
      float t01 = fmaxf(sv[0], sv[1]), t23 = fmaxf(sv[2], sv[3]);
      float t45 = fmaxf(sv[4], sv[5]), t67 = fmaxf(sv[6], sv[7]);
      float t89 = fmaxf(sv[8], sv[9]), tab = fmaxf(sv[10], sv[11]);
      float tcd = fmaxf(sv[12], sv[13]), tef = fmaxf(sv[14], sv[15]);
      float t = fmaxf(fmaxf(fmaxf(t01, t23), fmaxf(t45, t67)),
                      fmaxf(fmaxf(t89, tab), fmaxf(tcd, tef)));
      t = fmaxf(t, __shfl_xor(t, 32));

      // branchless rescale (a=1 when no growth; step0: a=exp2(-inf)=0)
      float mn = fmaxf(mrow, t);
      float a = exp2f(mrow - mn);
      mrow = mn;
      o[0] *= a;
      o[1] *= a;
      lrun *= a;

      float p[16];
      for (int r = 0; r < 16; r++) p[r] = exp2f(sv[r] - mrow);

      // l: in-lane sum + one shfl_xor(32) [R13-proven]
      float ssum = 0.f;
      for (int r = 0; r < 16; r++) ssum += p[r];
      lrun += ssum + __shfl_xor(ssum, 32);

      // pack; permlane swaps on DISTINCT values place own/partner halves so
      // {X0..X3},{X4..X7} ARE the PV B-frags for both lane halves
      unsigned X[8];
      for (int jj = 0; jj < 8; jj++) X[jj] = cvt_pk(p[2 * jj], p[2 * jj + 1]);
      swap32(X[0], X[2]);
      swap32(X[1], X[3]);
      swap32(X[4], X[6]);
      swap32(X[5], X[7]);

      union { unsigned u[4]; bf16x8 v; } bf0, bf1;
      bf0.u[0] = X[0]; bf0.u[1] = X[1]; bf0.u[2] = X[2]; bf0.u[3] = X[3];
      bf1.u[0] = X[4]; bf1.u[1] = X[5]; bf1.u[2] = X[6]; bf1.u[3] = X[7];

      for (int nt = 0; nt < 2; nt++) {
        o[nt] = mfma32(va[nt][0], bf0.v, o[nt]);
        o[nt] = mfma32(va[nt][1], bf1.v, o[nt]);
      }
    }

    // ---- per-wave partials; o stride 68 f32 ----
    float* ow = (float*)wbase;
    float* mw = (float*)(wbase + 8704);
    float* lw = (float*)(wbase + 8832);
    for (int nt = 0; nt < 2; nt++)
      for (int r = 0; r < 16; r++) {
        int d = nt * 32 + (r & 3) + 8 * (r >> 2) + 4 * hi;
        ow[q31 * 68 + d] = o[nt][r];
      }
    if (hi == 0) {
      mw[q31] = mrow;
      lw[q31] = lrun;
    }
    __syncthreads();

    // ---- LSE-merge across 8 waves (log2 domain): 512 thr x 4 = 32x64 ----
    for (int i = 0; i < 4; i++) {
      int e = tid + i * 512;
      int row = e >> 6;
      int d = e & 63;
      float M = -1e30f;
      for (int ww = 0; ww < NW; ww++)
        M = fmaxf(M, ((const float*)(smem + ww * WREG + 8704))[row]);
      float L = 0.f, O = 0.f;
      for (int ww = 0; ww < NW; ww++) {
        float mv = ((const float*)(smem + ww * WREG + 8704))[row];
        float f = exp2f(mv - M);
        L += f * ((const float*)(smem + ww * WREG + 8832))[row];
        O += f * ((const float*)(smem + ww * WREG))[row * 68 + d];
      }
      out[(rowbase + qb + row) * 64 + d] = O / L;
    }
    __syncthreads();  // merge reads done before next half reuses partials
  }
}

// ---------------------------------------------------------------------------
extern "C" void kernel_launch(void* const* d_in, const int* in_sizes, int n_in,
                              void* d_out, int out_size, void* d_ws, size_t ws_size,
                              hipStream_t stream) {
  const float* x = (const float*)d_in[0];
  const float* Wq = (const float*)d_in[1];
  const float* Wk = (const float*)d_in[2];
  const float* Wv = (const float*)d_in[3];
  float* out = (float*)d_out;

  char* ws = (char*)d_ws;
  unsigned short* Wt = (unsigned short*)(ws);                          // 384 KB
  unsigned short* qws = (unsigned short*)(ws + 393216);                // 2 MB
  unsigned short* kws = (unsigned short*)(ws + 393216 + 2097152);      // 2 MB
  unsigned short* vtws = (unsigned short*)(ws + 393216 + 2 * 2097152); // 2 MB

  prep_w<<<dim3(192), dim3(256), 0, stream>>>(Wq, Wk, Wv, Wt);
  proj_qkv<<<dim3(512), dim3(256), 0, stream>>>(x, Wt, qws, kws, vtws);
  attn_fwd<<<dim3(256), dim3(512), 0, stream>>>(qws, kws, vtws, out);
}